// Round 1
// baseline (4662.513 us; speedup 1.0000x reference)
//
#include <hip/hip_runtime.h>
#include <hip/hip_bf16.h>

#define B_ 256
#define T_ 512
#define E_ 128
#define H_ 256

typedef __attribute__((ext_vector_type(8))) short short8;
typedef __attribute__((ext_vector_type(4))) float f32x4;
typedef unsigned short u16;

#define MFMA_BF16(a, b, c) __builtin_amdgcn_mfma_f32_16x16x32_bf16((a), (b), (c), 0, 0, 0)

__device__ __forceinline__ u16 f2bf(float f) {
    union { float f; unsigned int u; } v; v.f = f;
    unsigned int u = v.u;
    unsigned int r = (u + 0x7fffu + ((u >> 16) & 1u)) >> 16;  // RNE
    return (u16)r;
}

// ---------------- phase 1a: fp32 -> bf16 weight conversion ----------------
__global__ void f32_to_bf16_kernel(const float* __restrict__ src, u16* __restrict__ dst, int n2) {
    int i = blockIdx.x * blockDim.x + threadIdx.x;
    if (i < n2) {
        float2 v = ((const float2*)src)[i];
        ushort2 o; o.x = f2bf(v.x); o.y = f2bf(v.y);
        ((ushort2*)dst)[i] = o;
    }
}

// ---------------- phase 1b: embedding gather -> bf16 [T][B][E] ----------------
__global__ void gather_emb_kernel(const int* __restrict__ x, const float* __restrict__ emb,
                                  u16* __restrict__ out) {
    int gid = blockIdx.x * 256 + threadIdx.x;  // one thread = 2 elems
    int pc  = gid & 63;                        // pair column: e = 2*pc
    int row = gid >> 6;                        // row = t*B + b
    int t = row >> 8;                          // B_ == 256
    int b = row & 255;
    int tok = x[b * T_ + t];
    float2 v = *(const float2*)(emb + (size_t)tok * E_ + pc * 2);
    ushort2 o; o.x = f2bf(v.x); o.y = f2bf(v.y);
    *(ushort2*)(out + (size_t)row * E_ + pc * 2) = o;
}

// ---------------- phase 2: persistent GRU recurrence ----------------
// grid = 32 blocks: blockIdx>>4 = dir (0 fwd, 1 bwd), blockIdx&15 = 16-row batch tile.
// block = 512 threads = 8 waves; wave wv owns hidden units [wv*32, wv*32+32) i.e.
// gate columns {u, 256+u, 512+u}. MFMA 16x16x32 bf16:
//   A[m=lane&15][k=quad*8+j], B[n=lane&15][k=quad*8+j], D col=lane&15 row=quad*4+reg.
__launch_bounds__(512, 1)
__global__ void gru_kernel(const u16* __restrict__ emb,   // [T][B][E] bf16
                           const u16* __restrict__ wih,   // [2][768][128] bf16
                           const u16* __restrict__ whh,   // [2][768][256] bf16
                           const float* __restrict__ bih_f, const float* __restrict__ bhh_f,
                           const float* __restrict__ bih_b, const float* __restrict__ bhh_b,
                           const int* __restrict__ lengths,
                           float* __restrict__ hcat) {    // [B][512] fp32
    const int dir    = blockIdx.x >> 4;
    const int b_base = (blockIdx.x & 15) << 4;
    const int wv     = threadIdx.x >> 6;
    const int lane   = threadIdx.x & 63;
    const int nl     = lane & 15;
    const int quad   = lane >> 4;

    __shared__ u16 hbuf[2][16][264];   // double-buffered h (bf16), +8 pad

    const u16* wih_d = wih + (size_t)dir * (768 * 128);
    const u16* whh_d = whh + (size_t)dir * (768 * 256);
    const float* bih = dir ? bih_b : bih_f;
    const float* bhh = dir ? bhh_b : bhh_f;

    int u[2]; u[0] = wv * 32 + nl; u[1] = u[0] + 16;

    float bias_r[2], bias_z[2], bias_nx[2], bias_nh[2];
    const u16 *pih_r[2], *pih_z[2], *pih_n[2], *phh_r[2], *phh_z[2], *phh_n[2];
#pragma unroll
    for (int hh = 0; hh < 2; hh++) {
        int uu = u[hh];
        bias_r[hh]  = bih[uu]       + bhh[uu];
        bias_z[hh]  = bih[256 + uu] + bhh[256 + uu];
        bias_nx[hh] = bih[512 + uu];            // b_ih_n stays outside r*(...)
        bias_nh[hh] = bhh[512 + uu];            // b_hh_n goes inside r*(...)
        pih_r[hh] = wih_d + (size_t)uu * 128 + quad * 8;
        pih_z[hh] = wih_d + (size_t)(256 + uu) * 128 + quad * 8;
        pih_n[hh] = wih_d + (size_t)(512 + uu) * 128 + quad * 8;
        phh_r[hh] = whh_d + (size_t)uu * 256 + quad * 8;
        phh_z[hh] = whh_d + (size_t)(256 + uu) * 256 + quad * 8;
        phh_n[hh] = whh_d + (size_t)(512 + uu) * 256 + quad * 8;
    }

    int len[4];
#pragma unroll
    for (int rr = 0; rr < 4; rr++) len[rr] = lengths[b_base + quad * 4 + rr];

    float hreg[2][4];   // fp32 master copy of h for this lane's (row, unit) pairs
#pragma unroll
    for (int hh = 0; hh < 2; hh++)
#pragma unroll
        for (int rr = 0; rr < 4; rr++) hreg[hh][rr] = 0.f;

    u16* hz = &hbuf[0][0][0];
    for (int i = threadIdx.x; i < 2 * 16 * 264; i += 512) hz[i] = 0;
    __syncthreads();

    for (int s = 0; s < T_; s++) {
        const int t = dir ? (T_ - 1 - s) : s;
        const int cur = s & 1, nxt = cur ^ 1;

        f32x4 ar[2]  = {{0,0,0,0},{0,0,0,0}};
        f32x4 az[2]  = {{0,0,0,0},{0,0,0,0}};
        f32x4 anx[2] = {{0,0,0,0},{0,0,0,0}};   // ih contribution to n-gate
        f32x4 anh[2] = {{0,0,0,0},{0,0,0,0}};   // hh contribution to n-gate

        // input projection: A = emb[t] tile (global), B = w_ih rows
        const u16* erow = emb + ((size_t)t * B_ + b_base + nl) * E_ + quad * 8;
#pragma unroll
        for (int kt = 0; kt < 4; kt++) {
            short8 a = *(const short8*)(erow + kt * 32);
#pragma unroll
            for (int hh = 0; hh < 2; hh++) {
                short8 br = *(const short8*)(pih_r[hh] + kt * 32);
                short8 bz = *(const short8*)(pih_z[hh] + kt * 32);
                short8 bn = *(const short8*)(pih_n[hh] + kt * 32);
                ar[hh]  = MFMA_BF16(a, br, ar[hh]);
                az[hh]  = MFMA_BF16(a, bz, az[hh]);
                anx[hh] = MFMA_BF16(a, bn, anx[hh]);
            }
        }
        // recurrent projection: A = h (LDS, bf16 mirror), B = w_hh rows
        const u16* hrow = &hbuf[cur][nl][quad * 8];
#pragma unroll
        for (int kt = 0; kt < 8; kt++) {
            short8 a = *(const short8*)(hrow + kt * 32);
#pragma unroll
            for (int hh = 0; hh < 2; hh++) {
                short8 br = *(const short8*)(phh_r[hh] + kt * 32);
                short8 bz = *(const short8*)(phh_z[hh] + kt * 32);
                short8 bn = *(const short8*)(phh_n[hh] + kt * 32);
                ar[hh]  = MFMA_BF16(a, br, ar[hh]);
                az[hh]  = MFMA_BF16(a, bz, az[hh]);
                anh[hh] = MFMA_BF16(a, bn, anh[hh]);
            }
        }

        // gates + masked update (fp32, per-lane: rows quad*4+rr, units u[hh])
#pragma unroll
        for (int hh = 0; hh < 2; hh++) {
#pragma unroll
            for (int rr = 0; rr < 4; rr++) {
                float r = 1.f / (1.f + __expf(-(ar[hh][rr] + bias_r[hh])));
                float z = 1.f / (1.f + __expf(-(az[hh][rr] + bias_z[hh])));
                float npre = anx[hh][rr] + bias_nx[hh] + r * (anh[hh][rr] + bias_nh[hh]);
                float nn = 1.f - 2.f / (1.f + __expf(2.f * npre));
                float hn = (1.f - z) * nn + z * hreg[hh][rr];
                if (t < len[rr]) hreg[hh][rr] = hn;   // ragged mask (fwd freeze / bwd hold-0)
                hbuf[nxt][quad * 4 + rr][u[hh]] = f2bf(hreg[hh][rr]);
            }
        }
        __syncthreads();
    }

#pragma unroll
    for (int hh = 0; hh < 2; hh++)
#pragma unroll
        for (int rr = 0; rr < 4; rr++)
            hcat[(size_t)(b_base + quad * 4 + rr) * 512 + dir * 256 + u[hh]] = hreg[hh][rr];
}

// ---------------- phase 3: FC head + row L2-normalize ----------------
__global__ void fc_head_kernel(const float* __restrict__ hcat,
                               const float* __restrict__ fc1w, const float* __restrict__ fc1b,
                               const float* __restrict__ fc2w, const float* __restrict__ fc2b,
                               float* __restrict__ out) {
    int row = blockIdx.x;
    int tid = threadIdx.x;  // 128
    __shared__ float hrow[512];
    __shared__ float hid[128];

    float4 hv = *(const float4*)(hcat + (size_t)row * 512 + tid * 4);
    *(float4*)(hrow + tid * 4) = hv;
    __syncthreads();

    float acc = fc1b[tid];
    const float* wrow = fc1w + (size_t)tid * 512;
#pragma unroll 4
    for (int k = 0; k < 512; k += 4) {
        float4 w = *(const float4*)(wrow + k);
        acc += w.x * hrow[k] + w.y * hrow[k + 1] + w.z * hrow[k + 2] + w.w * hrow[k + 3];
    }
    hid[tid] = fmaxf(acc, 0.f);
    __syncthreads();

    if (tid < 64) {
        float a2 = fc2b[tid];
        const float* w2 = fc2w + (size_t)tid * 128;
#pragma unroll 4
        for (int k = 0; k < 128; k += 4) {
            float4 w = *(const float4*)(w2 + k);
            a2 += w.x * hid[k] + w.y * hid[k + 1] + w.z * hid[k + 2] + w.w * hid[k + 3];
        }
        float ss = a2 * a2;
#pragma unroll
        for (int off = 32; off > 0; off >>= 1) ss += __shfl_down(ss, off);
        ss = __shfl(ss, 0);
        float scale = 1.f / fmaxf(sqrtf(ss), 1e-12f);
        out[(size_t)row * 64 + tid] = a2 * scale;
    }
}

// ---------------- launcher ----------------
// ws layout (bytes):
//   emb_bf  [T][B][E] u16 : 33,554,432
//   wih_bf  [2][768][128] : 393,216
//   whh_bf  [2][768][256] : 786,432
//   hcat    [B][512] f32  : 524,288        total ~35.3 MB
#define OFF_EMB  ((size_t)0)
#define OFF_WIH  ((size_t)33554432)
#define OFF_WHH  ((size_t)(33554432 + 393216))
#define OFF_HCAT ((size_t)(33554432 + 393216 + 786432))

extern "C" void kernel_launch(void* const* d_in, const int* in_sizes, int n_in,
                              void* d_out, int out_size, void* d_ws, size_t ws_size,
                              hipStream_t stream) {
    const int*   x      = (const int*)d_in[0];
    const int*   lens   = (const int*)d_in[1];
    const float* embedding = (const float*)d_in[2];
    const float* w_ih_f = (const float*)d_in[3];
    const float* w_hh_f = (const float*)d_in[4];
    const float* b_ih_f = (const float*)d_in[5];
    const float* b_hh_f = (const float*)d_in[6];
    const float* w_ih_b = (const float*)d_in[7];
    const float* w_hh_b = (const float*)d_in[8];
    const float* b_ih_b = (const float*)d_in[9];
    const float* b_hh_b = (const float*)d_in[10];
    const float* fc1_w  = (const float*)d_in[11];
    const float* fc1_b  = (const float*)d_in[12];
    const float* fc2_w  = (const float*)d_in[13];
    const float* fc2_b  = (const float*)d_in[14];
    float* out = (float*)d_out;

    char* ws = (char*)d_ws;
    u16*   emb_bf = (u16*)(ws + OFF_EMB);
    u16*   wih_bf = (u16*)(ws + OFF_WIH);
    u16*   whh_bf = (u16*)(ws + OFF_WHH);
    float* hcat   = (float*)(ws + OFF_HCAT);

    // weight conversions: w_ih 98304 elems each, w_hh 196608 elems each
    f32_to_bf16_kernel<<<192, 256, 0, stream>>>(w_ih_f, wih_bf, 49152);
    f32_to_bf16_kernel<<<192, 256, 0, stream>>>(w_ih_b, wih_bf + 98304, 49152);
    f32_to_bf16_kernel<<<384, 256, 0, stream>>>(w_hh_f, whh_bf, 98304);
    f32_to_bf16_kernel<<<384, 256, 0, stream>>>(w_hh_b, whh_bf + 196608, 98304);

    // embedding gather -> bf16 [T][B][E]
    gather_emb_kernel<<<32768, 256, 0, stream>>>(x, embedding, emb_bf);

    // recurrence: 32 persistent workgroups (16 batch tiles x 2 directions)
    gru_kernel<<<32, 512, 0, stream>>>(emb_bf, wih_bf, whh_bf,
                                       b_ih_f, b_hh_f, b_ih_b, b_hh_b,
                                       lens, hcat);

    // FC head + normalize
    fc_head_kernel<<<256, 128, 0, stream>>>(hcat, fc1_w, fc1_b, fc2_w, fc2_b, out);
}